// Round 1
// baseline (330.545 us; speedup 1.0000x reference)
//
#include <hip/hip_runtime.h>
#include <hip/hip_bf16.h>
#include <stdint.h>

// Problem constants
#define NB 16
#define TT 512
#define HH 64
#define CC 64
#define OO 64
#define KK 9
#define EE 256

typedef float f32x4 __attribute__((ext_vector_type(4)));
typedef __bf16 bf16x8 __attribute__((ext_vector_type(8)));
typedef unsigned short u16;
typedef unsigned int u32;

__device__ __forceinline__ u16 f2bf(float f) {
    u32 u = __float_as_uint(f);
    u32 r = (u + 0x7fffu + ((u >> 16) & 1u)) >> 16;
    return (u16)r;
}

// ---------------------------------------------------------------- k_adj
// Block n: build dense adj[n][64][64] from 256 edges via LDS atomics.
__global__ __launch_bounds__(256) void k_adj(const int* __restrict__ edges,
                                             float* __restrict__ adj) {
    __shared__ float a[64 * 64];
    const int n = blockIdx.x;
    for (int i = threadIdx.x; i < 4096; i += 256) a[i] = 0.f;
    __syncthreads();
    {
        int r = edges[n * 512 + threadIdx.x];        // edges[n][0][e]
        int c = edges[n * 512 + 256 + threadIdx.x];  // edges[n][1][e]
        atomicAdd(&a[r * 64 + c], 1.0f);
    }
    __syncthreads();
    for (int i = threadIdx.x; i < 4096; i += 256) adj[n * 4096 + i] = a[i];
}

// ---------------------------------------------------------------- k_pack
// Pre-swizzle W_lin (B[c][o]) and W_tcn (B_kk[o'][o]) into MFMA B-fragment
// order: frag idx [.. ][s][j][lane][jj]  ->  B[32s+8*(lane>>4)+jj][16j+(lane&15)]
__global__ __launch_bounds__(256) void k_pack(const float* __restrict__ Wlin,
                                              const float* __restrict__ Wtcn,
                                              u16* __restrict__ wlin_p,
                                              u16* __restrict__ wtcn_p) {
    int idx = blockIdx.x * 256 + threadIdx.x;
    if (idx < 4096) {
        int jj = idx & 7, l = (idx >> 3) & 63, j = (idx >> 9) & 3, s = idx >> 11;
        int o = j * 16 + (l & 15);
        int c = s * 32 + (l >> 4) * 8 + jj;
        wlin_p[idx] = f2bf(Wlin[o * 64 + c]);
    }
    int i2 = idx - 4096;
    if (i2 >= 0 && i2 < 36864) {
        int jj = i2 & 7, l = (i2 >> 3) & 63, j = (i2 >> 9) & 3, s = (i2 >> 11) & 1, kk = i2 >> 12;
        int o = j * 16 + (l & 15);
        int op = s * 32 + (l >> 4) * 8 + jj;
        wtcn_p[i2] = f2bf(Wtcn[(o * 64 + op) * 9 + kk]);  // W_tcn[o][o'][kk][0]
    }
}

// ---------------------------------------------------------------- k_attn_gcn
// One block per (n,t). Fuses: a1/a2 dots, leaky-relu + h-softmax + adj -> diag,
// support GEMM (bf16 MFMA), bias, diag scale, BN1, ReLU, bf16 store to
// z[n][h][t][o].
__global__ __launch_bounds__(256) void k_attn_gcn(
    const float* __restrict__ X, const float* __restrict__ adj,
    const float* __restrict__ w1g, const float* __restrict__ b1g,
    const float* __restrict__ w2g, const float* __restrict__ b2g,
    const float* __restrict__ blin, const u16* __restrict__ wlin_p,
    const float* __restrict__ g1, const float* __restrict__ be1,
    u16* __restrict__ z) {
    __shared__ __align__(16) u16 Xbf[64 * 72];   // bf16 X tile, row pad 72
    __shared__ __align__(16) float U[6336];      // adjs[64*65] | p1[64*17] | p2[64*17]
    __shared__ float A1[64], A2[64], DG[64];
    float* const adjs = U;
    float* const p1 = U + 4160;
    float* const p2 = U + 4160 + 1088;

    const int tid = threadIdx.x;
    const int n = blockIdx.x >> 9, t = blockIdx.x & 511;
    const float* Xrow = X + (size_t)(n * 512 + t) * 4096;  // X[n][t][.][.]

    // P1: stage X as bf16, compute a1/a2 partial dots from registers, stage adj
    {
        const int c4 = tid & 15;
        const int r0 = tid >> 4;
        float4 wv1 = *(const float4*)(w1g + c4 * 4);
        float4 wv2 = *(const float4*)(w2g + c4 * 4);
#pragma unroll
        for (int i = 0; i < 4; i++) {
            int h = r0 + 16 * i;
            float4 xv = *(const float4*)(Xrow + h * 64 + c4 * 4);
            p1[h * 17 + c4] = xv.x * wv1.x + xv.y * wv1.y + xv.z * wv1.z + xv.w * wv1.w;
            p2[h * 17 + c4] = xv.x * wv2.x + xv.y * wv2.y + xv.z * wv2.z + xv.w * wv2.w;
            uint2 pk;
            pk.x = (u32)f2bf(xv.x) | ((u32)f2bf(xv.y) << 16);
            pk.y = (u32)f2bf(xv.z) | ((u32)f2bf(xv.w) << 16);
            *(uint2*)(&Xbf[h * 72 + c4 * 4]) = pk;
        }
        const float* adjn = adj + n * 4096;
#pragma unroll
        for (int i = 0; i < 16; i++) {
            int idx = tid + 256 * i;
            adjs[(idx >> 6) * 65 + (idx & 63)] = adjn[idx];
        }
    }
    __syncthreads();

    // P2: reduce partial dots -> a1[h], a2[h]
    if (tid < 64) {
        float s = 0.f;
#pragma unroll
        for (int i = 0; i < 16; i++) s += p1[tid * 17 + i];
        A1[tid] = s + b1g[0];
    } else if (tid < 128) {
        int h = tid - 64;
        float s = 0.f;
#pragma unroll
        for (int i = 0; i < 16; i++) s += p2[h * 17 + i];
        A2[h] = s + b2g[0];
    }
    __syncthreads();

    // P3: diag[h] = sum_k adj[h,k] e(k,h) / sum_k e(k,h) + 1,
    //     e(k,h) = exp(leaky_relu(a1[k]+a2[h], 0.01))
    {
        int h = tid >> 2, p = tid & 3;
        float a2h = A2[h];
        float num = 0.f, den = 0.f;
#pragma unroll
        for (int i = 0; i < 16; i++) {
            int k = p * 16 + i;
            float sv = A1[k] + a2h;
            sv = sv > 0.f ? sv : 0.01f * sv;
            float e = __expf(sv);
            den += e;
            num += adjs[h * 65 + k] * e;
        }
        p1[h * 17 + p] = num;
        p2[h * 17 + p] = den;
    }
    __syncthreads();
    if (tid < 64) {
        float num = p1[tid * 17 + 0] + p1[tid * 17 + 1] + p1[tid * 17 + 2] + p1[tid * 17 + 3];
        float den = p2[tid * 17 + 0] + p2[tid * 17 + 1] + p2[tid * 17 + 2] + p2[tid * 17 + 3];
        DG[tid] = num / den + 1.0f;
    }
    __syncthreads();

    // P4: support = X @ W_lin^T via MFMA. Wave w owns h-rows [16w, 16w+16).
    const int w = tid >> 6, l = tid & 63;
    const int col = l & 15, q = l >> 4;
    f32x4 zv = {0.f, 0.f, 0.f, 0.f};
    f32x4 acc[4] = {zv, zv, zv, zv};
#pragma unroll
    for (int s = 0; s < 2; s++) {
        bf16x8 a = *(const bf16x8*)(&Xbf[(16 * w + col) * 72 + s * 32 + q * 8]);
#pragma unroll
        for (int j = 0; j < 4; j++) {
            bf16x8 b = *(const bf16x8*)(&wlin_p[((s * 4 + j) * 64 + l) * 8]);
            acc[j] = __builtin_amdgcn_mfma_f32_16x16x32_bf16(a, b, acc[j], 0, 0, 0);
        }
    }

    // Epilogue: (acc + b_lin)*diag*bn1_scale + bn1_shift, ReLU, bf16 -> LDS tile
    const float rsf = 1.0f / sqrtf(1.0f + 1e-5f);
    u16* OT = (u16*)U;  // [64][72], overlaps adjs (dead)
#pragma unroll
    for (int j = 0; j < 4; j++) {
        int o = 16 * j + col;
        float s1 = g1[o] * rsf;
        float bb = be1[o];
        float bl = blin[o];
#pragma unroll
        for (int r = 0; r < 4; r++) {
            int h = 16 * w + q * 4 + r;
            float v = (acc[j][r] + bl) * DG[h] * s1 + bb;
            v = v > 0.f ? v : 0.f;
            OT[h * 72 + 16 * j + col] = f2bf(v);
        }
    }
    __syncthreads();
    // coalesced store: z[n][h][t][0..64)
    {
        int h = tid >> 2, seg = tid & 3;
        u16* zrow = z + ((size_t)(n * 64 + h) * 512 + t) * 64;
        uint4 v0 = *(const uint4*)(&OT[h * 72 + seg * 16]);
        uint4 v1 = *(const uint4*)(&OT[h * 72 + seg * 16 + 8]);
        *(uint4*)(zrow + seg * 16) = v0;
        *(uint4*)(zrow + seg * 16 + 8) = v1;
    }
}

// ---------------------------------------------------------------- k_tcn
// One block per (n, h, half-T). Temporal conv as 9 accumulated GEMMs
// (K=576 total) with bf16 MFMA; epilogue: +bias, BN2, +X residual, ReLU.
__global__ __launch_bounds__(256) void k_tcn(
    const u16* __restrict__ z, const u16* __restrict__ wtcn_p,
    const float* __restrict__ X, const float* __restrict__ btcn,
    const float* __restrict__ g2, const float* __restrict__ be2,
    float* __restrict__ out) {
    __shared__ __align__(16) u16 As[264 * 72];  // rows t in [tb-4, tb+260), pad 72

    const int tid = threadIdx.x;
    const int bid = blockIdx.x;
    const int n = bid >> 7, h = (bid >> 1) & 63, tb = (bid & 1) * 256;
    const u16* zp = z + (size_t)(n * 64 + h) * 512 * 64;

    // stage A (zero halo outside [0,512))
#pragma unroll
    for (int i = 0; i < 9; i++) {
        int idx = tid + 256 * i;  // over 264*8 = 2112 16B-chunks
        if (idx < 2112) {
            int r = idx >> 3, c8 = idx & 7;
            int tg = tb - 4 + r;
            uint4 v = make_uint4(0u, 0u, 0u, 0u);
            if (tg >= 0 && tg < 512) v = *(const uint4*)(zp + tg * 64 + c8 * 8);
            *(uint4*)(&As[r * 72 + c8 * 8]) = v;
        }
    }
    __syncthreads();

    const int w = tid >> 6, l = tid & 63;
    const int col = l & 15, q = l >> 4;
    f32x4 zv = {0.f, 0.f, 0.f, 0.f};
    f32x4 acc[4][4];  // [mt][j]
#pragma unroll
    for (int mt = 0; mt < 4; mt++)
#pragma unroll
        for (int j = 0; j < 4; j++) acc[mt][j] = zv;

    for (int kk = 0; kk < 9; kk++) {
#pragma unroll
        for (int s = 0; s < 2; s++) {
            bf16x8 b[4];
#pragma unroll
            for (int j = 0; j < 4; j++)
                b[j] = *(const bf16x8*)(&wtcn_p[(((kk * 2 + s) * 4 + j) * 64 + l) * 8]);
            bf16x8 a[4];
#pragma unroll
            for (int mt = 0; mt < 4; mt++) {
                int row = 64 * w + 16 * mt + col + kk;  // LDS row = m + kk
                a[mt] = *(const bf16x8*)(&As[row * 72 + s * 32 + q * 8]);
            }
#pragma unroll
            for (int mt = 0; mt < 4; mt++)
#pragma unroll
                for (int j = 0; j < 4; j++)
                    acc[mt][j] = __builtin_amdgcn_mfma_f32_16x16x32_bf16(a[mt], b[j], acc[mt][j], 0, 0, 0);
        }
    }

    // epilogue
    const float rsf = 1.0f / sqrtf(1.0f + 1e-5f);
    float s2[4], c2[4];
#pragma unroll
    for (int j = 0; j < 4; j++) {
        int o = 16 * j + col;
        float s = g2[o] * rsf;
        s2[j] = s;
        c2[j] = btcn[o] * s + be2[o];
    }
#pragma unroll
    for (int mt = 0; mt < 4; mt++) {
#pragma unroll
        for (int r = 0; r < 4; r++) {
            int tt = tb + 64 * w + 16 * mt + 4 * q + r;
#pragma unroll
            for (int j = 0; j < 4; j++) {
                int o = 16 * j + col;
                size_t off = ((size_t)(n * 512 + tt) * 64 + h) * 64 + o;
                float v = acc[mt][j][r] * s2[j] + c2[j] + X[off];
                out[off] = v > 0.f ? v : 0.f;
            }
        }
    }
}

// ---------------------------------------------------------------- launch
extern "C" void kernel_launch(void* const* d_in, const int* in_sizes, int n_in,
                              void* d_out, int out_size, void* d_ws, size_t ws_size,
                              hipStream_t stream) {
    const float* X    = (const float*)d_in[0];
    const int*  edges = (const int*)d_in[1];   // JAX x64 disabled -> int32
    const float* w1   = (const float*)d_in[2];
    const float* b1   = (const float*)d_in[3];
    const float* w2   = (const float*)d_in[4];
    const float* b2   = (const float*)d_in[5];
    const float* Wlin = (const float*)d_in[6];
    const float* blin = (const float*)d_in[7];
    const float* g1   = (const float*)d_in[8];
    const float* be1  = (const float*)d_in[9];
    const float* Wtcn = (const float*)d_in[10];
    const float* btcn = (const float*)d_in[11];
    const float* g2   = (const float*)d_in[12];
    const float* be2  = (const float*)d_in[13];
    float* out = (float*)d_out;

    char* ws = (char*)d_ws;
    float* adj    = (float*)ws;                              // 262144 B
    u16*   wlin_p = (u16*)(ws + 262144);                     // 8192 B
    u16*   wtcn_p = (u16*)(ws + 262144 + 8192);              // 73728 B
    u16*   z      = (u16*)(ws + 262144 + 8192 + 73728);      // 67108864 B

    hipLaunchKernelGGL(k_adj, dim3(16), dim3(256), 0, stream, edges, adj);
    hipLaunchKernelGGL(k_pack, dim3(160), dim3(256), 0, stream, Wlin, Wtcn, wlin_p, wtcn_p);
    hipLaunchKernelGGL(k_attn_gcn, dim3(16 * 512), dim3(256), 0, stream,
                       X, adj, w1, b1, w2, b2, blin, wlin_p, g1, be1, z);
    hipLaunchKernelGGL(k_tcn, dim3(16 * 64 * 2), dim3(256), 0, stream,
                       z, wtcn_p, X, btcn, g2, be2, out);
}

// Round 2
// 319.669 us; speedup vs baseline: 1.0340x; 1.0340x over previous
//
#include <hip/hip_runtime.h>
#include <hip/hip_bf16.h>
#include <stdint.h>

// Problem constants: N=16, T=512, H=C=O=64, K=9, E=256
typedef float f32x4 __attribute__((ext_vector_type(4)));
typedef __bf16 bf16x8 __attribute__((ext_vector_type(8)));
typedef unsigned short u16;
typedef unsigned int u32;

__device__ __forceinline__ u16 f2bf(float f) {
    u32 u = __float_as_uint(f);
    u32 r = (u + 0x7fffu + ((u >> 16) & 1u)) >> 16;
    return (u16)r;
}

// ---------------------------------------------------------------- k_adj
// Block n: dense adj[n][64][64] from 256 edges via LDS atomics.
__global__ __launch_bounds__(256) void k_adj(const int* __restrict__ edges,
                                             float* __restrict__ adj) {
    __shared__ float a[64 * 64];
    const int n = blockIdx.x;
    for (int i = threadIdx.x; i < 4096; i += 256) a[i] = 0.f;
    __syncthreads();
    {
        int r = edges[n * 512 + threadIdx.x];        // edges[n][0][e]
        int c = edges[n * 512 + 256 + threadIdx.x];  // edges[n][1][e]
        atomicAdd(&a[r * 64 + c], 1.0f);
    }
    __syncthreads();
    for (int i = threadIdx.x; i < 4096; i += 256) adj[n * 4096 + i] = a[i];
}

// ---------------------------------------------------------------- k_pack
// MFMA B-fragment order: [..][s][j][lane][jj] -> B[32s+8*(lane>>4)+jj][16j+(lane&15)]
__global__ __launch_bounds__(256) void k_pack(const float* __restrict__ Wlin,
                                              const float* __restrict__ Wtcn,
                                              u16* __restrict__ wlin_p,
                                              u16* __restrict__ wtcn_p) {
    int idx = blockIdx.x * 256 + threadIdx.x;
    if (idx < 4096) {
        int jj = idx & 7, l = (idx >> 3) & 63, j = (idx >> 9) & 3, s = idx >> 11;
        int o = j * 16 + (l & 15);
        int c = s * 32 + (l >> 4) * 8 + jj;
        wlin_p[idx] = f2bf(Wlin[o * 64 + c]);
    }
    int i2 = idx - 4096;
    if (i2 >= 0 && i2 < 36864) {
        int jj = i2 & 7, l = (i2 >> 3) & 63, j = (i2 >> 9) & 3, s = (i2 >> 11) & 1, kk = i2 >> 12;
        int o = j * 16 + (l & 15);
        int op = s * 32 + (l >> 4) * 8 + jj;
        wtcn_p[i2] = f2bf(Wtcn[(o * 64 + op) * 9 + kk]);  // W_tcn[o][o'][kk][0]
    }
}

// ---------------------------------------------------------------- k_attn
// One block per (n,t): a1/a2 dots, leaky-relu + h-softmax + adj row-dot ->
// diag[n][h][t] (t-contiguous layout for k_gcn_tcn staging).
__global__ __launch_bounds__(256) void k_attn(
    const float* __restrict__ X, const float* __restrict__ adj,
    const float* __restrict__ w1g, const float* __restrict__ b1g,
    const float* __restrict__ w2g, const float* __restrict__ b2g,
    float* __restrict__ diag) {
    __shared__ float adjs[64 * 65];
    __shared__ float p1[64 * 17], p2[64 * 17];
    __shared__ float A1[64], A2[64];

    const int tid = threadIdx.x;
    const int n = blockIdx.x >> 9, t = blockIdx.x & 511;
    const float* Xrow = X + (size_t)(n * 512 + t) * 4096;

    // P1: partial a1/a2 dots + adj stage
    {
        const int c4 = tid & 15;
        const int r0 = tid >> 4;
        float4 wv1 = *(const float4*)(w1g + c4 * 4);
        float4 wv2 = *(const float4*)(w2g + c4 * 4);
#pragma unroll
        for (int i = 0; i < 4; i++) {
            int h = r0 + 16 * i;
            float4 xv = *(const float4*)(Xrow + h * 64 + c4 * 4);
            p1[h * 17 + c4] = xv.x * wv1.x + xv.y * wv1.y + xv.z * wv1.z + xv.w * wv1.w;
            p2[h * 17 + c4] = xv.x * wv2.x + xv.y * wv2.y + xv.z * wv2.z + xv.w * wv2.w;
        }
        const float* adjn = adj + n * 4096;
#pragma unroll
        for (int i = 0; i < 16; i++) {
            int idx = tid + 256 * i;
            adjs[(idx >> 6) * 65 + (idx & 63)] = adjn[idx];
        }
    }
    __syncthreads();

    // P2: reduce -> A1[h], A2[h]
    if (tid < 64) {
        float s = 0.f;
#pragma unroll
        for (int i = 0; i < 16; i++) s += p1[tid * 17 + i];
        A1[tid] = s + b1g[0];
    } else if (tid < 128) {
        int h = tid - 64;
        float s = 0.f;
#pragma unroll
        for (int i = 0; i < 16; i++) s += p2[h * 17 + i];
        A2[h] = s + b2g[0];
    }
    __syncthreads();

    // P3: diag[h] = sum_k adj[h,k] e(k,h) / sum_k e(k,h) + 1
    {
        int h = tid >> 2, p = tid & 3;
        float a2h = A2[h];
        float num = 0.f, den = 0.f;
#pragma unroll
        for (int i = 0; i < 16; i++) {
            int k = p * 16 + i;
            float sv = A1[k] + a2h;
            sv = sv > 0.f ? sv : 0.01f * sv;
            float e = __expf(sv);
            den += e;
            num += adjs[h * 65 + k] * e;
        }
        p1[h * 17 + p] = num;
        p2[h * 17 + p] = den;
    }
    __syncthreads();
    if (tid < 64) {
        float num = p1[tid * 17 + 0] + p1[tid * 17 + 1] + p1[tid * 17 + 2] + p1[tid * 17 + 3];
        float den = p2[tid * 17 + 0] + p2[tid * 17 + 1] + p2[tid * 17 + 2] + p2[tid * 17 + 3];
        diag[((size_t)(n * 64 + tid)) * 512 + t] = num / den + 1.0f;
    }
}

// ---------------------------------------------------------------- k_gcn_tcn
// One block per (n, h, quarter-T=128). Stage X rows [tb-4, tb+140) as bf16,
// support GEMM (in-place z in LDS: diag*BN1*ReLU), then K=9 temporal conv
// GEMM; epilogue +bias BN2 + f32 X residual + ReLU -> out.
__global__ __launch_bounds__(256) void k_gcn_tcn(
    const float* __restrict__ X, const float* __restrict__ diag,
    const u16* __restrict__ wlin_p, const float* __restrict__ blin,
    const float* __restrict__ g1, const float* __restrict__ be1,
    const u16* __restrict__ wtcn_p, const float* __restrict__ btcn,
    const float* __restrict__ g2, const float* __restrict__ be2,
    float* __restrict__ out) {
    __shared__ __align__(16) u16 As[144 * 72];  // row r <-> t = tb-4+r, pad 72
    __shared__ float DGs[144];

    const int tid = threadIdx.x;
    const int bid = blockIdx.x;
    const int n = bid >> 8, h = (bid >> 2) & 63, tb = (bid & 3) * 128;
    const float* Xbase = X + ((size_t)(n * 512) * 64 + h) * 64;  // + t*4096 + c

    // stage X (f32 -> bf16), zero halo outside [0,512)
#pragma unroll
    for (int i = 0; i < 9; i++) {
        int idx = tid + 256 * i;  // 144 rows * 16 quads = 2304
        int r = idx >> 4, c4 = idx & 15;
        int tg = tb - 4 + r;
        float4 xv = make_float4(0.f, 0.f, 0.f, 0.f);
        if (tg >= 0 && tg < 512) xv = *(const float4*)(Xbase + (size_t)tg * 4096 + c4 * 4);
        uint2 pk;
        pk.x = (u32)f2bf(xv.x) | ((u32)f2bf(xv.y) << 16);
        pk.y = (u32)f2bf(xv.z) | ((u32)f2bf(xv.w) << 16);
        *(uint2*)(&As[r * 72 + c4 * 4]) = pk;
    }
    if (tid < 144) {
        int tg = tb - 4 + tid;
        DGs[tid] = (tg >= 0 && tg < 512) ? diag[((size_t)(n * 64 + h)) * 512 + tg] : 0.f;
    }
    __syncthreads();

    const int w = tid >> 6, l = tid & 63;
    const int col = l & 15, q = l >> 4;
    const float rsf = 1.0f / sqrtf(1.0f + 1e-5f);
    const f32x4 zv = {0.f, 0.f, 0.f, 0.f};

    // support GEMM, z written in place over X rows (wave-private m-tiles)
    for (int mt = w; mt < 9; mt += 4) {
        f32x4 acc[4] = {zv, zv, zv, zv};
#pragma unroll
        for (int s = 0; s < 2; s++) {
            bf16x8 a = *(const bf16x8*)(&As[(16 * mt + col) * 72 + s * 32 + q * 8]);
#pragma unroll
            for (int j = 0; j < 4; j++) {
                bf16x8 b = *(const bf16x8*)(&wlin_p[((s * 4 + j) * 64 + l) * 8]);
                acc[j] = __builtin_amdgcn_mfma_f32_16x16x32_bf16(a, b, acc[j], 0, 0, 0);
            }
        }
#pragma unroll
        for (int j = 0; j < 4; j++) {
            int o = 16 * j + col;
            float s1 = g1[o] * rsf;
            float bb = be1[o];
            float bl = blin[o];
#pragma unroll
            for (int rr = 0; rr < 4; rr++) {
                int row = 16 * mt + q * 4 + rr;
                int tg = tb - 4 + row;
                float v = (acc[j][rr] + bl) * DGs[row] * s1 + bb;
                v = v > 0.f ? v : 0.f;
                if (tg < 0 || tg >= 512) v = 0.f;  // conv halo must be zero
                As[row * 72 + o] = f2bf(v);
            }
        }
    }
    __syncthreads();

    // temporal conv: wave w -> output local rows [32w, 32w+32)
    f32x4 acc2[2][4];
#pragma unroll
    for (int mt = 0; mt < 2; mt++)
#pragma unroll
        for (int j = 0; j < 4; j++) acc2[mt][j] = zv;

    for (int kk = 0; kk < 9; kk++) {
#pragma unroll
        for (int s = 0; s < 2; s++) {
            bf16x8 b[4];
#pragma unroll
            for (int j = 0; j < 4; j++)
                b[j] = *(const bf16x8*)(&wtcn_p[(((kk * 2 + s) * 4 + j) * 64 + l) * 8]);
            bf16x8 a[2];
#pragma unroll
            for (int mt = 0; mt < 2; mt++) {
                int row = 32 * w + 16 * mt + col + kk;  // <= 135
                a[mt] = *(const bf16x8*)(&As[row * 72 + s * 32 + q * 8]);
            }
#pragma unroll
            for (int mt = 0; mt < 2; mt++)
#pragma unroll
                for (int j = 0; j < 4; j++)
                    acc2[mt][j] = __builtin_amdgcn_mfma_f32_16x16x32_bf16(a[mt], b[j], acc2[mt][j], 0, 0, 0);
        }
    }

    // epilogue: BN2(+bias) + residual X (f32, L2-warm) + ReLU
    float s2[4], c2[4];
#pragma unroll
    for (int j = 0; j < 4; j++) {
        int o = 16 * j + col;
        float s = g2[o] * rsf;
        s2[j] = s;
        c2[j] = btcn[o] * s + be2[o];
    }
#pragma unroll
    for (int mt = 0; mt < 2; mt++) {
#pragma unroll
        for (int rr = 0; rr < 4; rr++) {
            int tt = tb + 32 * w + 16 * mt + 4 * q + rr;
#pragma unroll
            for (int j = 0; j < 4; j++) {
                int o = 16 * j + col;
                size_t off = ((size_t)(n * 512 + tt) * 64 + h) * 64 + o;
                float v = acc2[mt][j][rr] * s2[j] + c2[j] + X[off];
                out[off] = v > 0.f ? v : 0.f;
            }
        }
    }
}

// ---------------------------------------------------------------- launch
extern "C" void kernel_launch(void* const* d_in, const int* in_sizes, int n_in,
                              void* d_out, int out_size, void* d_ws, size_t ws_size,
                              hipStream_t stream) {
    const float* X    = (const float*)d_in[0];
    const int*  edges = (const int*)d_in[1];
    const float* w1   = (const float*)d_in[2];
    const float* b1   = (const float*)d_in[3];
    const float* w2   = (const float*)d_in[4];
    const float* b2   = (const float*)d_in[5];
    const float* Wlin = (const float*)d_in[6];
    const float* blin = (const float*)d_in[7];
    const float* g1   = (const float*)d_in[8];
    const float* be1  = (const float*)d_in[9];
    const float* Wtcn = (const float*)d_in[10];
    const float* btcn = (const float*)d_in[11];
    const float* g2   = (const float*)d_in[12];
    const float* be2  = (const float*)d_in[13];
    float* out = (float*)d_out;

    char* ws = (char*)d_ws;
    float* adj    = (float*)ws;                          // 262144 B
    u16*   wlin_p = (u16*)(ws + 262144);                 // 8192 B
    u16*   wtcn_p = (u16*)(ws + 262144 + 8192);          // 73728 B
    float* diag   = (float*)(ws + 262144 + 8192 + 73728);// 2097152 B

    hipLaunchKernelGGL(k_adj, dim3(16), dim3(256), 0, stream, edges, adj);
    hipLaunchKernelGGL(k_pack, dim3(160), dim3(256), 0, stream, Wlin, Wtcn, wlin_p, wtcn_p);
    hipLaunchKernelGGL(k_attn, dim3(16 * 512), dim3(256), 0, stream,
                       X, adj, w1, b1, w2, b2, diag);
    hipLaunchKernelGGL(k_gcn_tcn, dim3(16 * 64 * 4), dim3(256), 0, stream,
                       X, diag, wlin_p, blin, g1, be1, wtcn_p, btcn, g2, be2, out);
}